// Round 5
// baseline (5662.830 us; speedup 1.0000x reference)
//
#include <hip/hip_runtime.h>

#define TSTEPS 8192
#define H 51
#define SE 32                    // timesteps per barrier epoch (R23: 16 -> 32)
#define HB 8                     // half-block size for wave1/wave2 staging
#define NEPOCH (TSTEPS / SE + 3) // 4 pipeline stages -> +3 epochs

typedef float  f2 __attribute__((ext_vector_type(2)));
typedef float  f4 __attribute__((ext_vector_type(4)));
typedef int    i4 __attribute__((ext_vector_type(4)));
typedef int    i2 __attribute__((ext_vector_type(2)));
typedef _Float16 h2 __attribute__((ext_vector_type(2)));

__device__ __forceinline__ int rl_i(int v, int k) { return __builtin_amdgcn_readlane(v, k); }
__device__ __forceinline__ h2 asp(int v) { union { int i; h2 h; } u; u.i = v; return u.h; }
__device__ __forceinline__ int ash(h2 v) { union { int i; h2 h; } u; u.h = v; return u.i; }

__device__ __forceinline__ float fdot2(h2 a, h2 b, float c) {
#if __has_builtin(__builtin_amdgcn_fdot2)
    return __builtin_amdgcn_fdot2(a, b, c, false);
#else
    return fmaf((float)a[0], (float)b[0], fmaf((float)a[1], (float)b[1], c));
#endif
}
__device__ __forceinline__ float sigmoidf_fast(float x) {
    return __builtin_amdgcn_rcpf(1.0f + __expf(-x));
}
__device__ __forceinline__ float tanhf_fast(float x) {
    x = fminf(fmaxf(x, -15.0f), 15.0f);
    float t = __expf(-2.0f * x);
    return (1.0f - t) * __builtin_amdgcn_rcpf(1.0f + t);
}
__device__ __forceinline__ int packpair(const float* Wrow, int j) {
    const float w0 = (2 * j < H) ? Wrow[2 * j] : 0.0f;
    const float w1 = (2 * j + 1 < H) ? Wrow[2 * j + 1] : 0.0f;
    h2 p; p[0] = (_Float16)w0; p[1] = (_Float16)w1; return ash(p);
}
// R21: pure-VALU pack (DPP quad_perm neighbor + RNE f16 pair), no DS pipe.
// Measured: bank-conflict 65536 -> 0, -232 us. Even lane 2j holds
// {h[2j], h[2j+1]}; DOT26 broadcasts from lane 2j.
__device__ __forceinline__ int packpairs_dpp(float hval) {
    const int nbi = __builtin_amdgcn_mov_dpp(__float_as_int(hval), 0xB1, 0xF, 0xF, true);
    h2 pk; pk[0] = (_Float16)hval; pk[1] = (_Float16)__int_as_float(nbi);
    return ash(pk);
}

// R23 = R21 inner bodies byte-identical (R22's three "removals" all REVERTED:
// they regressed +432 us -- fifth datapoint that ANY edit inside the step
// bodies loses; only structural moves pay). Structural deltas vs R21:
//   - SE 16 -> 32: halves the per-step share of barrier+drain (~-20 cyc/step)
//   - sh_out deleted; wave3 (off-path) stores lane-0 results directly to
//     global (fire-and-forget) -> frees 32KB LDS so SE=32 z2a fits:
//     LDS = 32K(x) + 16K(hpk1) + 64K(z2a) + 16K(h2f) = 128 KiB
//   - wave1/wave2 process 4 half-blocks of HB=8 (identical per-iter bodies;
//     za/hp staging stays 32 VGPR, below the spill cliff)
// Pipeline (R13 lineage):
//   wave0 @e: steps 32e..32e+31 : h1 = cell1(Whh1.h1 + x)  [in-wave serial]
//   wave2 @e: steps 32(e-1)+j   : z2a = Wih2.h1            [32 indep dots]
//   wave1 @e: steps 32(e-2)+j   : u2 dot (in-wave) + cell2 [in-wave serial]
//   wave3 @e: steps 32(e-3)+j   : out = Wlin.h2 + blin     [off-path, global]
// Invariants: (1) no DS ops on the serial chain (R21). (2) asm "+v" PIN once
// prevents remat/sink (R7). (3) step bodies are sacred (R14-R17, R22).
#define DECLG(g) i4 wq##g##_0, wq##g##_1, wq##g##_2, wq##g##_3, wq##g##_4, wq##g##_5; i2 wq##g##_6;
#define LOADG(g, RP) { const float* _r = (RP); \
    i4 t0 = {packpair(_r,0),  packpair(_r,1),  packpair(_r,2),  packpair(_r,3)};  wq##g##_0 = t0; \
    i4 t1 = {packpair(_r,4),  packpair(_r,5),  packpair(_r,6),  packpair(_r,7)};  wq##g##_1 = t1; \
    i4 t2 = {packpair(_r,8),  packpair(_r,9),  packpair(_r,10), packpair(_r,11)}; wq##g##_2 = t2; \
    i4 t3 = {packpair(_r,12), packpair(_r,13), packpair(_r,14), packpair(_r,15)}; wq##g##_3 = t3; \
    i4 t4 = {packpair(_r,16), packpair(_r,17), packpair(_r,18), packpair(_r,19)}; wq##g##_4 = t4; \
    i4 t5 = {packpair(_r,20), packpair(_r,21), packpair(_r,22), packpair(_r,23)}; wq##g##_5 = t5; \
    i2 t6 = {packpair(_r,24), packpair(_r,25)};                                   wq##g##_6 = t6; }
#define PING(g) asm("" : "+v"(wq##g##_0), "+v"(wq##g##_1), "+v"(wq##g##_2), \
                        "+v"(wq##g##_3), "+v"(wq##g##_4), "+v"(wq##g##_5), "+v"(wq##g##_6));
// two interleaved accumulator sets: a* (even j) and b* (odd j) -> depth 13
#define DJA(j,q,e) { const h2 _hb = asp(rl_i(_hs, 2*(j))); \
    a0 = fdot2(asp(wq0_##q[e]), _hb, a0); \
    a1 = fdot2(asp(wq1_##q[e]), _hb, a1); \
    a2 = fdot2(asp(wq2_##q[e]), _hb, a2); \
    a3 = fdot2(asp(wq3_##q[e]), _hb, a3); }
#define DJB(j,q,e) { const h2 _hb = asp(rl_i(_hs, 2*(j))); \
    b0 = fdot2(asp(wq0_##q[e]), _hb, b0); \
    b1 = fdot2(asp(wq1_##q[e]), _hb, b1); \
    b2 = fdot2(asp(wq2_##q[e]), _hb, b2); \
    b3 = fdot2(asp(wq3_##q[e]), _hb, b3); }
#define DOT26 \
    DJA(0,0,0) DJB(1,0,1) DJA(2,0,2) DJB(3,0,3) DJA(4,1,0) DJB(5,1,1) DJA(6,1,2) DJB(7,1,3) \
    DJA(8,2,0) DJB(9,2,1) DJA(10,2,2) DJB(11,2,3) DJA(12,3,0) DJB(13,3,1) DJA(14,3,2) DJB(15,3,3) \
    DJA(16,4,0) DJB(17,4,1) DJA(18,4,2) DJB(19,4,3) DJA(20,5,0) DJB(21,5,1) DJA(22,5,2) DJB(23,5,3) \
    DJA(24,6,0) DJB(25,6,1)

__global__ __launch_bounds__(256) __attribute__((amdgpu_waves_per_eu(1, 1)))
void lstm2_b32_kernel(const float* __restrict__ x,
                      const float* __restrict__ Wih1,
                      const float* __restrict__ Whh1,
                      const float* __restrict__ bih1,
                      const float* __restrict__ bhh1,
                      const float* __restrict__ Wih2,
                      const float* __restrict__ Whh2,
                      const float* __restrict__ bih2,
                      const float* __restrict__ bhh2,
                      const float* __restrict__ Wlin,
                      const float* __restrict__ blin,
                      float* __restrict__ out)
{
    __shared__ __align__(16) float sh_x[TSTEPS];
    __shared__ __align__(16) int   sh_hpk1[2][SE][64];  // packed h1 (wave0 -> wave2)
    __shared__ __align__(16) f4    sh_z2a[2][SE][64];   // raw Wih2.h1 (wave2 -> wave1)
    __shared__ __align__(16) float sh_h2f[2][SE][64];   // f32 h2 (wave1 -> wave3)

    const int tid  = threadIdx.x;
    const int wave = tid >> 6;
    const int lane = tid & 63;
    const int row  = (lane < H) ? lane : (H - 1);

    for (int i = tid; i < TSTEPS / 4; i += 256)
        ((f4*)sh_x)[i] = ((const f4*)x)[i];

    // ---- per-wave matrix as 104 packed f16-pair registers, pinned once ----
    const float* Mp = (wave == 0) ? Whh1 : (wave == 1) ? Whh2 : Wih2;
    DECLG(0) DECLG(1) DECLG(2) DECLG(3)
    LOADG(0, Mp + (0 * H + row) * H)
    LOADG(1, Mp + (1 * H + row) * H)
    LOADG(2, Mp + (2 * H + row) * H)
    LOADG(3, Mp + (3 * H + row) * H)
    PING(0) PING(1) PING(2) PING(3)

    f4 b1v, wx4, b2v;
#pragma unroll
    for (int g = 0; g < 4; ++g) {
        b1v[g] = bih1[g * H + row] + bhh1[g * H + row];
        wx4[g] = Wih1[g * H + row];
        b2v[g] = bih2[g * H + row] + bhh2[g * H + row];
    }
    const float wlin = (lane < H) ? Wlin[lane] : 0.0f;
    const float bl   = blin[0];

    if (tid < 64) {
#pragma unroll
        for (int b = 0; b < 2; ++b)
#pragma unroll
            for (int j = 0; j < SE; ++j) {
                sh_hpk1[b][j][tid] = 0;
                sh_z2a[b][j][tid] = (f4)0.0f;
                sh_h2f[b][j][tid] = 0.0f;
            }
    }
    float c1 = 0.0f, c2 = 0.0f;
    int hpk1reg = 0, hpk2reg = 0;
    __syncthreads();

#pragma unroll 1
    for (int e = 0; e < NEPOCH; ++e) {
        if (wave == 0) {
            // ---- steps 32e..32e+31: layer-1 self-loop, fully in-wave ----
            if (e < TSTEPS / SE) {
                f4 xs[SE / 4];
#pragma unroll
                for (int q = 0; q < SE / 4; ++q) xs[q] = ((const f4*)sh_x)[(SE / 4) * e + q];
#pragma unroll
                for (int j = 0; j < SE; ++j) {
                    const float xv = xs[j >> 2][j & 3];
                    // x-FMA folded into acc init (off the post-dot tail)
                    float a0 = fmaf(wx4[0], xv, b1v[0]);
                    float a1 = fmaf(wx4[1], xv, b1v[1]);
                    float a2 = fmaf(wx4[2], xv, b1v[2]);
                    float a3 = fmaf(wx4[3], xv, b1v[3]);
                    float b0 = 0.0f, b1 = 0.0f, b2 = 0.0f, b3 = 0.0f;
                    const int _hs = hpk1reg;
                    DOT26
                    const float ig = sigmoidf_fast(a0 + b0), fg = sigmoidf_fast(a1 + b1);
                    const float gg = tanhf_fast(a2 + b2),    og = sigmoidf_fast(a3 + b3);
                    c1 = fmaf(fg, c1, ig * gg);
                    const float h1n = (lane < H) ? og * tanhf_fast(c1) : 0.0f;
                    hpk1reg = packpairs_dpp(h1n);
                    sh_hpk1[e & 1][j][lane] = hpk1reg;
                }
            }
        } else if (wave == 2) {
            // ---- steps 32(e-1)+j: z2a = Wih2.h1 (32 indep dots, 4 blocks) ----
            if (e >= 1 && e <= TSTEPS / SE) {
#pragma unroll
                for (int hb = 0; hb < SE / HB; ++hb) {
                    int hp[HB];
#pragma unroll
                    for (int jj = 0; jj < HB; ++jj)
                        hp[jj] = sh_hpk1[(e - 1) & 1][hb * HB + jj][lane];
#pragma unroll
                    for (int jj = 0; jj < HB; ++jj) {
                        const int _hs = hp[jj];
                        float a0 = 0.0f, a1 = 0.0f, a2 = 0.0f, a3 = 0.0f;
                        float b0 = 0.0f, b1 = 0.0f, b2 = 0.0f, b3 = 0.0f;
                        DOT26
                        f4 z; z[0] = a0 + b0; z[1] = a1 + b1; z[2] = a2 + b2; z[3] = a3 + b3;
                        sh_z2a[e & 1][hb * HB + jj][lane] = z;
                    }
                }
            }
        } else if (wave == 1) {
            // ---- steps 32(e-2)+j: u2 dot (in-wave h2 self-loop) + cell2 ----
            // four half-blocks of 8: za prefetch stays at 32 VGPR (spill cliff)
            if (e >= 2 && e <= TSTEPS / SE + 1) {
#pragma unroll
                for (int hb = 0; hb < SE / HB; ++hb) {
                    f4 za[HB];
#pragma unroll
                    for (int jj = 0; jj < HB; ++jj)
                        za[jj] = sh_z2a[(e - 1) & 1][hb * HB + jj][lane];
#pragma unroll
                    for (int jj = 0; jj < HB; ++jj) {
                        float a0 = b2v[0], a1 = b2v[1], a2 = b2v[2], a3 = b2v[3];
                        float b0 = 0.0f, b1 = 0.0f, b2 = 0.0f, b3 = 0.0f;
                        const int _hs = hpk2reg;
                        DOT26
                        const float ig = sigmoidf_fast(za[jj][0] + a0 + b0);
                        const float fg = sigmoidf_fast(za[jj][1] + a1 + b1);
                        const float gg = tanhf_fast   (za[jj][2] + a2 + b2);
                        const float og = sigmoidf_fast(za[jj][3] + a3 + b3);
                        c2 = fmaf(fg, c2, ig * gg);
                        const float h2n = (lane < H) ? og * tanhf_fast(c2) : 0.0f;
                        sh_h2f[e & 1][hb * HB + jj][lane] = h2n;
                        hpk2reg = packpairs_dpp(h2n);
                    }
                }
            }
        } else {
            // ---- steps 32(e-3)+j: out = Wlin.h2 + blin (off-path, direct
            // global store -- sh_out deleted to fit SE=32 in LDS) ----
            if (e >= 3) {
                const int base = (e - 3) * SE;
                float p[SE];
#pragma unroll
                for (int j = 0; j < SE; ++j)
                    p[j] = sh_h2f[(e - 1) & 1][j][lane] * wlin;
#pragma unroll
                for (int off = 32; off >= 1; off >>= 1) {
#pragma unroll
                    for (int j = 0; j < SE; ++j) p[j] += __shfl_down(p[j], off);
                }
                if (lane == 0) {
#pragma unroll
                    for (int j = 0; j < SE; ++j) out[base + j] = p[j] + bl;
                }
            }
        }
        __syncthreads();
    }
}

extern "C" void kernel_launch(void* const* d_in, const int* in_sizes, int n_in,
                              void* d_out, int out_size, void* d_ws, size_t ws_size,
                              hipStream_t stream) {
    const float* x    = (const float*)d_in[0];
    const float* Wih1 = (const float*)d_in[1];
    const float* Whh1 = (const float*)d_in[2];
    const float* bih1 = (const float*)d_in[3];
    const float* bhh1 = (const float*)d_in[4];
    const float* Wih2 = (const float*)d_in[5];
    const float* Whh2 = (const float*)d_in[6];
    const float* bih2 = (const float*)d_in[7];
    const float* bhh2 = (const float*)d_in[8];
    const float* Wlin = (const float*)d_in[9];
    const float* blin = (const float*)d_in[10];
    float* out = (float*)d_out;

    lstm2_b32_kernel<<<1, 256, 0, stream>>>(
        x, Wih1, Whh1, bih1, bhh1, Wih2, Whh2, bih2, bhh2, Wlin, blin, out);
}

// Round 6
// 3339.858 us; speedup vs baseline: 1.6955x; 1.6955x over previous
//
#include <hip/hip_runtime.h>

#define TSTEPS 8192
#define H 51
#define SE 32                    // timesteps per barrier epoch
#define NEPOCH (TSTEPS / SE + 3) // 4 pipeline stages -> +3 epochs

typedef float  f2 __attribute__((ext_vector_type(2)));
typedef float  f4 __attribute__((ext_vector_type(4)));
typedef int    i4 __attribute__((ext_vector_type(4)));
typedef int    i2 __attribute__((ext_vector_type(2)));
typedef _Float16 h2 __attribute__((ext_vector_type(2)));

__device__ __forceinline__ int rl_i(int v, int k) { return __builtin_amdgcn_readlane(v, k); }
__device__ __forceinline__ h2 asp(int v) { union { int i; h2 h; } u; u.i = v; return u.h; }
__device__ __forceinline__ int ash(h2 v) { union { int i; h2 h; } u; u.h = v; return u.i; }

__device__ __forceinline__ float fdot2(h2 a, h2 b, float c) {
#if __has_builtin(__builtin_amdgcn_fdot2)
    return __builtin_amdgcn_fdot2(a, b, c, false);
#else
    return fmaf((float)a[0], (float)b[0], fmaf((float)a[1], (float)b[1], c));
#endif
}
__device__ __forceinline__ float sigmoidf_fast(float x) {
    return __builtin_amdgcn_rcpf(1.0f + __expf(-x));
}
__device__ __forceinline__ float tanhf_fast(float x) {
    x = fminf(fmaxf(x, -15.0f), 15.0f);
    float t = __expf(-2.0f * x);
    return (1.0f - t) * __builtin_amdgcn_rcpf(1.0f + t);
}
__device__ __forceinline__ int packpair(const float* Wrow, int j) {
    const float w0 = (2 * j < H) ? Wrow[2 * j] : 0.0f;
    const float w1 = (2 * j + 1 < H) ? Wrow[2 * j + 1] : 0.0f;
    h2 p; p[0] = (_Float16)w0; p[1] = (_Float16)w1; return ash(p);
}
// R21: pure-VALU pack (DPP quad_perm neighbor + RNE f16 pair), no DS pipe.
// Measured: bank-conflict 65536 -> 0, -232 us. Even lane 2j holds
// {h[2j], h[2j+1]}; DOT26 broadcasts from lane 2j.
__device__ __forceinline__ int packpairs_dpp(float hval) {
    const int nbi = __builtin_amdgcn_mov_dpp(__float_as_int(hval), 0xB1, 0xF, 0xF, true);
    h2 pk; pk[0] = (_Float16)hval; pk[1] = (_Float16)__int_as_float(nbi);
    return ash(pk);
}

// R24: I$-thrash fix. R23 (SE=32 fully unrolled) halved VALUBusy and doubled
// time: per-epoch code = SE x ~1.2KB x 3 waves ~ 120KB >> 32KB shared L1I,
// and 4 waves stream 4 disjoint code regions every epoch. Retro-explains R20
// (SE 8->16 rocprof-flat: barrier savings eaten by I$ misses).
// Fix: roll the per-step loops (#pragma unroll 1) -- each wave's step body
// (byte-identical to R21's) appears ONCE (~8KB total kernel hot code), with
// a one-iteration software prefetch of each wave's per-step LDS operand
// (xv / hp / za) so the rolled loop adds no serial-chain latency. SE=32 then
// gives max barrier amortization for free (LDS 128KB, sh_out deleted: wave3
// stores lane-0 results straight to global, off-path).
// Pipeline (R13 lineage):
//   wave0 @e: steps 32e..32e+31 : h1 = cell1(Whh1.h1 + x)  [in-wave serial]
//   wave2 @e: steps 32(e-1)+j   : z2a = Wih2.h1            [32 indep dots]
//   wave1 @e: steps 32(e-2)+j   : u2 dot (in-wave) + cell2 [in-wave serial]
//   wave3 @e: steps 32(e-3)+j   : out = Wlin.h2 + blin     [off-path, global]
// Invariants: (1) no DS ops on the serial chain (R21). (2) asm "+v" PIN once
// prevents remat/sink (R7). (3) step bodies are sacred (R14-R17, R22).
// (4) NEW: total hot code must fit shared L1I (~32KB) -- never fully unroll
// the step loop (R23).
#define DECLG(g) i4 wq##g##_0, wq##g##_1, wq##g##_2, wq##g##_3, wq##g##_4, wq##g##_5; i2 wq##g##_6;
#define LOADG(g, RP) { const float* _r = (RP); \
    i4 t0 = {packpair(_r,0),  packpair(_r,1),  packpair(_r,2),  packpair(_r,3)};  wq##g##_0 = t0; \
    i4 t1 = {packpair(_r,4),  packpair(_r,5),  packpair(_r,6),  packpair(_r,7)};  wq##g##_1 = t1; \
    i4 t2 = {packpair(_r,8),  packpair(_r,9),  packpair(_r,10), packpair(_r,11)}; wq##g##_2 = t2; \
    i4 t3 = {packpair(_r,12), packpair(_r,13), packpair(_r,14), packpair(_r,15)}; wq##g##_3 = t3; \
    i4 t4 = {packpair(_r,16), packpair(_r,17), packpair(_r,18), packpair(_r,19)}; wq##g##_4 = t4; \
    i4 t5 = {packpair(_r,20), packpair(_r,21), packpair(_r,22), packpair(_r,23)}; wq##g##_5 = t5; \
    i2 t6 = {packpair(_r,24), packpair(_r,25)};                                   wq##g##_6 = t6; }
#define PING(g) asm("" : "+v"(wq##g##_0), "+v"(wq##g##_1), "+v"(wq##g##_2), \
                        "+v"(wq##g##_3), "+v"(wq##g##_4), "+v"(wq##g##_5), "+v"(wq##g##_6));
// two interleaved accumulator sets: a* (even j) and b* (odd j) -> depth 13
#define DJA(j,q,e) { const h2 _hb = asp(rl_i(_hs, 2*(j))); \
    a0 = fdot2(asp(wq0_##q[e]), _hb, a0); \
    a1 = fdot2(asp(wq1_##q[e]), _hb, a1); \
    a2 = fdot2(asp(wq2_##q[e]), _hb, a2); \
    a3 = fdot2(asp(wq3_##q[e]), _hb, a3); }
#define DJB(j,q,e) { const h2 _hb = asp(rl_i(_hs, 2*(j))); \
    b0 = fdot2(asp(wq0_##q[e]), _hb, b0); \
    b1 = fdot2(asp(wq1_##q[e]), _hb, b1); \
    b2 = fdot2(asp(wq2_##q[e]), _hb, b2); \
    b3 = fdot2(asp(wq3_##q[e]), _hb, b3); }
#define DOT26 \
    DJA(0,0,0) DJB(1,0,1) DJA(2,0,2) DJB(3,0,3) DJA(4,1,0) DJB(5,1,1) DJA(6,1,2) DJB(7,1,3) \
    DJA(8,2,0) DJB(9,2,1) DJA(10,2,2) DJB(11,2,3) DJA(12,3,0) DJB(13,3,1) DJA(14,3,2) DJB(15,3,3) \
    DJA(16,4,0) DJB(17,4,1) DJA(18,4,2) DJB(19,4,3) DJA(20,5,0) DJB(21,5,1) DJA(22,5,2) DJB(23,5,3) \
    DJA(24,6,0) DJB(25,6,1)

__global__ __launch_bounds__(256) __attribute__((amdgpu_waves_per_eu(1, 1)))
void lstm2_r24_kernel(const float* __restrict__ x,
                      const float* __restrict__ Wih1,
                      const float* __restrict__ Whh1,
                      const float* __restrict__ bih1,
                      const float* __restrict__ bhh1,
                      const float* __restrict__ Wih2,
                      const float* __restrict__ Whh2,
                      const float* __restrict__ bih2,
                      const float* __restrict__ bhh2,
                      const float* __restrict__ Wlin,
                      const float* __restrict__ blin,
                      float* __restrict__ out)
{
    __shared__ __align__(16) float sh_x[TSTEPS];
    __shared__ __align__(16) int   sh_hpk1[2][SE][64];  // packed h1 (wave0 -> wave2)
    __shared__ __align__(16) f4    sh_z2a[2][SE][64];   // raw Wih2.h1 (wave2 -> wave1)
    __shared__ __align__(16) float sh_h2f[2][SE][64];   // f32 h2 (wave1 -> wave3)

    const int tid  = threadIdx.x;
    const int wave = tid >> 6;
    const int lane = tid & 63;
    const int row  = (lane < H) ? lane : (H - 1);

    for (int i = tid; i < TSTEPS / 4; i += 256)
        ((f4*)sh_x)[i] = ((const f4*)x)[i];

    // ---- per-wave matrix as 104 packed f16-pair registers, pinned once ----
    const float* Mp = (wave == 0) ? Whh1 : (wave == 1) ? Whh2 : Wih2;
    DECLG(0) DECLG(1) DECLG(2) DECLG(3)
    LOADG(0, Mp + (0 * H + row) * H)
    LOADG(1, Mp + (1 * H + row) * H)
    LOADG(2, Mp + (2 * H + row) * H)
    LOADG(3, Mp + (3 * H + row) * H)
    PING(0) PING(1) PING(2) PING(3)

    f4 b1v, wx4, b2v;
#pragma unroll
    for (int g = 0; g < 4; ++g) {
        b1v[g] = bih1[g * H + row] + bhh1[g * H + row];
        wx4[g] = Wih1[g * H + row];
        b2v[g] = bih2[g * H + row] + bhh2[g * H + row];
    }
    const float wlin = (lane < H) ? Wlin[lane] : 0.0f;
    const float bl   = blin[0];

    if (tid < 64) {
#pragma unroll
        for (int b = 0; b < 2; ++b)
            for (int j = 0; j < SE; ++j) {
                sh_hpk1[b][j][tid] = 0;
                sh_z2a[b][j][tid] = (f4)0.0f;
                sh_h2f[b][j][tid] = 0.0f;
            }
    }
    float c1 = 0.0f, c2 = 0.0f;
    int hpk1reg = 0, hpk2reg = 0;
    __syncthreads();

#pragma unroll 1
    for (int e = 0; e < NEPOCH; ++e) {
        if (wave == 0) {
            // ---- steps 32e..32e+31: layer-1 self-loop, fully in-wave ----
            if (e < TSTEPS / SE) {
                const int xbase = SE * e;
                float xv_cur = sh_x[xbase];
#pragma unroll 1
                for (int j = 0; j < SE; ++j) {
                    const int jn = (j + 1 < SE) ? (j + 1) : j;
                    const float xv_next = sh_x[xbase + jn];  // prefetch, used next iter
                    // x-FMA folded into acc init (off the post-dot tail)
                    float a0 = fmaf(wx4[0], xv_cur, b1v[0]);
                    float a1 = fmaf(wx4[1], xv_cur, b1v[1]);
                    float a2 = fmaf(wx4[2], xv_cur, b1v[2]);
                    float a3 = fmaf(wx4[3], xv_cur, b1v[3]);
                    float b0 = 0.0f, b1 = 0.0f, b2 = 0.0f, b3 = 0.0f;
                    const int _hs = hpk1reg;
                    DOT26
                    const float ig = sigmoidf_fast(a0 + b0), fg = sigmoidf_fast(a1 + b1);
                    const float gg = tanhf_fast(a2 + b2),    og = sigmoidf_fast(a3 + b3);
                    c1 = fmaf(fg, c1, ig * gg);
                    const float h1n = (lane < H) ? og * tanhf_fast(c1) : 0.0f;
                    hpk1reg = packpairs_dpp(h1n);
                    sh_hpk1[e & 1][j][lane] = hpk1reg;
                    xv_cur = xv_next;
                }
            }
        } else if (wave == 2) {
            // ---- steps 32(e-1)+j: z2a = Wih2.h1 (32 indep dots, rolled) ----
            if (e >= 1 && e <= TSTEPS / SE) {
                const int rb = (e - 1) & 1;
                int hp_cur = sh_hpk1[rb][0][lane];
#pragma unroll 1
                for (int j = 0; j < SE; ++j) {
                    const int jn = (j + 1 < SE) ? (j + 1) : j;
                    const int hp_next = sh_hpk1[rb][jn][lane];  // prefetch
                    const int _hs = hp_cur;
                    float a0 = 0.0f, a1 = 0.0f, a2 = 0.0f, a3 = 0.0f;
                    float b0 = 0.0f, b1 = 0.0f, b2 = 0.0f, b3 = 0.0f;
                    DOT26
                    f4 z; z[0] = a0 + b0; z[1] = a1 + b1; z[2] = a2 + b2; z[3] = a3 + b3;
                    sh_z2a[e & 1][j][lane] = z;
                    hp_cur = hp_next;
                }
            }
        } else if (wave == 1) {
            // ---- steps 32(e-2)+j: u2 dot (in-wave h2 self-loop) + cell2 ----
            if (e >= 2 && e <= TSTEPS / SE + 1) {
                const int rb = (e - 1) & 1;
                f4 za_cur = sh_z2a[rb][0][lane];
#pragma unroll 1
                for (int j = 0; j < SE; ++j) {
                    const int jn = (j + 1 < SE) ? (j + 1) : j;
                    const f4 za_next = sh_z2a[rb][jn][lane];  // prefetch
                    float a0 = b2v[0], a1 = b2v[1], a2 = b2v[2], a3 = b2v[3];
                    float b0 = 0.0f, b1 = 0.0f, b2 = 0.0f, b3 = 0.0f;
                    const int _hs = hpk2reg;
                    DOT26
                    const float ig = sigmoidf_fast(za_cur[0] + a0 + b0);
                    const float fg = sigmoidf_fast(za_cur[1] + a1 + b1);
                    const float gg = tanhf_fast   (za_cur[2] + a2 + b2);
                    const float og = sigmoidf_fast(za_cur[3] + a3 + b3);
                    c2 = fmaf(fg, c2, ig * gg);
                    const float h2n = (lane < H) ? og * tanhf_fast(c2) : 0.0f;
                    sh_h2f[e & 1][j][lane] = h2n;
                    hpk2reg = packpairs_dpp(h2n);
                    za_cur = za_next;
                }
            }
        } else {
            // ---- steps 32(e-3)+j: out = Wlin.h2 + blin (off-path, rolled,
            // direct global store) ----
            if (e >= 3) {
                const int base = (e - 3) * SE;
                const int rb = (e - 1) & 1;
#pragma unroll 1
                for (int j = 0; j < SE; ++j) {
                    float p = sh_h2f[rb][j][lane] * wlin;
#pragma unroll
                    for (int off = 32; off >= 1; off >>= 1)
                        p += __shfl_down(p, off);
                    if (lane == 0) out[base + j] = p + bl;
                }
            }
        }
        __syncthreads();
    }
}

extern "C" void kernel_launch(void* const* d_in, const int* in_sizes, int n_in,
                              void* d_out, int out_size, void* d_ws, size_t ws_size,
                              hipStream_t stream) {
    const float* x    = (const float*)d_in[0];
    const float* Wih1 = (const float*)d_in[1];
    const float* Whh1 = (const float*)d_in[2];
    const float* bih1 = (const float*)d_in[3];
    const float* bhh1 = (const float*)d_in[4];
    const float* Wih2 = (const float*)d_in[5];
    const float* Whh2 = (const float*)d_in[6];
    const float* bih2 = (const float*)d_in[7];
    const float* bhh2 = (const float*)d_in[8];
    const float* Wlin = (const float*)d_in[9];
    const float* blin = (const float*)d_in[10];
    float* out = (float*)d_out;

    lstm2_r24_kernel<<<1, 256, 0, stream>>>(
        x, Wih1, Whh1, bih1, bhh1, Wih2, Whh2, bih2, bhh2, Wlin, blin, out);
}

// Round 7
// 3030.196 us; speedup vs baseline: 1.8688x; 1.1022x over previous
//
#include <hip/hip_runtime.h>

#define TSTEPS 8192
#define H 51
#define SE 32                    // timesteps per barrier epoch
#define HB 8                     // unrolled inner block (I$-sized, R19-proven)
#define NB (SE / HB)             // rolled outer blocks per epoch
#define NEPOCH (TSTEPS / SE + 3) // 4 pipeline stages -> +3 epochs

typedef float  f2 __attribute__((ext_vector_type(2)));
typedef float  f4 __attribute__((ext_vector_type(4)));
typedef int    i4 __attribute__((ext_vector_type(4)));
typedef int    i2 __attribute__((ext_vector_type(2)));
typedef _Float16 h2 __attribute__((ext_vector_type(2)));

__device__ __forceinline__ int rl_i(int v, int k) { return __builtin_amdgcn_readlane(v, k); }
__device__ __forceinline__ h2 asp(int v) { union { int i; h2 h; } u; u.i = v; return u.h; }
__device__ __forceinline__ int ash(h2 v) { union { int i; h2 h; } u; u.h = v; return u.i; }

__device__ __forceinline__ float fdot2(h2 a, h2 b, float c) {
#if __has_builtin(__builtin_amdgcn_fdot2)
    return __builtin_amdgcn_fdot2(a, b, c, false);
#else
    return fmaf((float)a[0], (float)b[0], fmaf((float)a[1], (float)b[1], c));
#endif
}
__device__ __forceinline__ float sigmoidf_fast(float x) {
    return __builtin_amdgcn_rcpf(1.0f + __expf(-x));
}
__device__ __forceinline__ float tanhf_fast(float x) {
    x = fminf(fmaxf(x, -15.0f), 15.0f);
    float t = __expf(-2.0f * x);
    return (1.0f - t) * __builtin_amdgcn_rcpf(1.0f + t);
}
__device__ __forceinline__ int packpair(const float* Wrow, int j) {
    const float w0 = (2 * j < H) ? Wrow[2 * j] : 0.0f;
    const float w1 = (2 * j + 1 < H) ? Wrow[2 * j + 1] : 0.0f;
    h2 p; p[0] = (_Float16)w0; p[1] = (_Float16)w1; return ash(p);
}
// R21: pure-VALU pack (DPP quad_perm neighbor + RNE f16 pair), no DS pipe.
// Measured: bank-conflict 65536 -> 0, -232 us. Even lane 2j holds
// {h[2j], h[2j+1]}; DOT26 broadcasts from lane 2j.
__device__ __forceinline__ int packpairs_dpp(float hval) {
    const int nbi = __builtin_amdgcn_mov_dpp(__float_as_int(hval), 0xB1, 0xF, 0xF, true);
    h2 pk; pk[0] = (_Float16)hval; pk[1] = (_Float16)__int_as_float(nbi);
    return ash(pk);
}

// R25: I$ x unroll-depth middle point. Ledger so far (rocprof):
//   R21  SE=16 full-unroll (~60KB code)  2940 us   <- best
//   R23  SE=32 full-unroll (~120KB)      5830 us   I$ thrash (VALUBusy halved)
//   R24  SE=32 full-roll   (~8KB)        3273 us   thrash fixed, +40cyc/step
//                                                  loop overhead
//   SE 8->16 was rocprof-flat => barrier amortization ~ 0; code size is the
//   binding constraint, loop overhead the second.
// R25 = SE=32, rolled outer (NB=4) x unrolled-8 inner blocks. Step bodies
// byte-identical to R21 (R14-R17/R22: bodies are sacred). Code ~= one 8-step
// block per wave ~= 30KB total (R19-proven fit); loop overhead amortized x8;
// operand staging back to batched form (hp[8]/za[8]/2xf4) off the chain.
// This is R23's structure with '#pragma unroll 1' on the block loops.
// Pipeline (R13 lineage):
//   wave0 @e: steps 32e..32e+31 : h1 = cell1(Whh1.h1 + x)  [in-wave serial]
//   wave2 @e: steps 32(e-1)+j   : z2a = Wih2.h1            [32 indep dots]
//   wave1 @e: steps 32(e-2)+j   : u2 dot (in-wave) + cell2 [in-wave serial]
//   wave3 @e: steps 32(e-3)+j   : out = Wlin.h2 + blin     [off-path, global]
// Invariants: (1) no DS ops on the serial chain (R21). (2) asm "+v" PIN once
// (R7). (3) step bodies sacred (R14-R17, R22). (4) hot code must fit L1I:
// never fully unroll an epoch (R23); never fully roll either (R24).
#define DECLG(g) i4 wq##g##_0, wq##g##_1, wq##g##_2, wq##g##_3, wq##g##_4, wq##g##_5; i2 wq##g##_6;
#define LOADG(g, RP) { const float* _r = (RP); \
    i4 t0 = {packpair(_r,0),  packpair(_r,1),  packpair(_r,2),  packpair(_r,3)};  wq##g##_0 = t0; \
    i4 t1 = {packpair(_r,4),  packpair(_r,5),  packpair(_r,6),  packpair(_r,7)};  wq##g##_1 = t1; \
    i4 t2 = {packpair(_r,8),  packpair(_r,9),  packpair(_r,10), packpair(_r,11)}; wq##g##_2 = t2; \
    i4 t3 = {packpair(_r,12), packpair(_r,13), packpair(_r,14), packpair(_r,15)}; wq##g##_3 = t3; \
    i4 t4 = {packpair(_r,16), packpair(_r,17), packpair(_r,18), packpair(_r,19)}; wq##g##_4 = t4; \
    i4 t5 = {packpair(_r,20), packpair(_r,21), packpair(_r,22), packpair(_r,23)}; wq##g##_5 = t5; \
    i2 t6 = {packpair(_r,24), packpair(_r,25)};                                   wq##g##_6 = t6; }
#define PING(g) asm("" : "+v"(wq##g##_0), "+v"(wq##g##_1), "+v"(wq##g##_2), \
                        "+v"(wq##g##_3), "+v"(wq##g##_4), "+v"(wq##g##_5), "+v"(wq##g##_6));
// two interleaved accumulator sets: a* (even j) and b* (odd j) -> depth 13
#define DJA(j,q,e) { const h2 _hb = asp(rl_i(_hs, 2*(j))); \
    a0 = fdot2(asp(wq0_##q[e]), _hb, a0); \
    a1 = fdot2(asp(wq1_##q[e]), _hb, a1); \
    a2 = fdot2(asp(wq2_##q[e]), _hb, a2); \
    a3 = fdot2(asp(wq3_##q[e]), _hb, a3); }
#define DJB(j,q,e) { const h2 _hb = asp(rl_i(_hs, 2*(j))); \
    b0 = fdot2(asp(wq0_##q[e]), _hb, b0); \
    b1 = fdot2(asp(wq1_##q[e]), _hb, b1); \
    b2 = fdot2(asp(wq2_##q[e]), _hb, b2); \
    b3 = fdot2(asp(wq3_##q[e]), _hb, b3); }
#define DOT26 \
    DJA(0,0,0) DJB(1,0,1) DJA(2,0,2) DJB(3,0,3) DJA(4,1,0) DJB(5,1,1) DJA(6,1,2) DJB(7,1,3) \
    DJA(8,2,0) DJB(9,2,1) DJA(10,2,2) DJB(11,2,3) DJA(12,3,0) DJB(13,3,1) DJA(14,3,2) DJB(15,3,3) \
    DJA(16,4,0) DJB(17,4,1) DJA(18,4,2) DJB(19,4,3) DJA(20,5,0) DJB(21,5,1) DJA(22,5,2) DJB(23,5,3) \
    DJA(24,6,0) DJB(25,6,1)

__global__ __launch_bounds__(256) __attribute__((amdgpu_waves_per_eu(1, 1)))
void lstm2_r25_kernel(const float* __restrict__ x,
                      const float* __restrict__ Wih1,
                      const float* __restrict__ Whh1,
                      const float* __restrict__ bih1,
                      const float* __restrict__ bhh1,
                      const float* __restrict__ Wih2,
                      const float* __restrict__ Whh2,
                      const float* __restrict__ bih2,
                      const float* __restrict__ bhh2,
                      const float* __restrict__ Wlin,
                      const float* __restrict__ blin,
                      float* __restrict__ out)
{
    __shared__ __align__(16) float sh_x[TSTEPS];
    __shared__ __align__(16) int   sh_hpk1[2][SE][64];  // packed h1 (wave0 -> wave2)
    __shared__ __align__(16) f4    sh_z2a[2][SE][64];   // raw Wih2.h1 (wave2 -> wave1)
    __shared__ __align__(16) float sh_h2f[2][SE][64];   // f32 h2 (wave1 -> wave3)

    const int tid  = threadIdx.x;
    const int wave = tid >> 6;
    const int lane = tid & 63;
    const int row  = (lane < H) ? lane : (H - 1);

    for (int i = tid; i < TSTEPS / 4; i += 256)
        ((f4*)sh_x)[i] = ((const f4*)x)[i];

    // ---- per-wave matrix as 104 packed f16-pair registers, pinned once ----
    const float* Mp = (wave == 0) ? Whh1 : (wave == 1) ? Whh2 : Wih2;
    DECLG(0) DECLG(1) DECLG(2) DECLG(3)
    LOADG(0, Mp + (0 * H + row) * H)
    LOADG(1, Mp + (1 * H + row) * H)
    LOADG(2, Mp + (2 * H + row) * H)
    LOADG(3, Mp + (3 * H + row) * H)
    PING(0) PING(1) PING(2) PING(3)

    f4 b1v, wx4, b2v;
#pragma unroll
    for (int g = 0; g < 4; ++g) {
        b1v[g] = bih1[g * H + row] + bhh1[g * H + row];
        wx4[g] = Wih1[g * H + row];
        b2v[g] = bih2[g * H + row] + bhh2[g * H + row];
    }
    const float wlin = (lane < H) ? Wlin[lane] : 0.0f;
    const float bl   = blin[0];

    if (tid < 64) {
        for (int b = 0; b < 2; ++b)
            for (int j = 0; j < SE; ++j) {
                sh_hpk1[b][j][tid] = 0;
                sh_z2a[b][j][tid] = (f4)0.0f;
                sh_h2f[b][j][tid] = 0.0f;
            }
    }
    float c1 = 0.0f, c2 = 0.0f;
    int hpk1reg = 0, hpk2reg = 0;
    __syncthreads();

#pragma unroll 1
    for (int e = 0; e < NEPOCH; ++e) {
        if (wave == 0) {
            // ---- steps 32e..32e+31: layer-1 self-loop, fully in-wave ----
            if (e < TSTEPS / SE) {
#pragma unroll 1
                for (int hb = 0; hb < NB; ++hb) {
                    const f4 xs0 = ((const f4*)sh_x)[(SE / 4) * e + 2 * hb];
                    const f4 xs1 = ((const f4*)sh_x)[(SE / 4) * e + 2 * hb + 1];
#pragma unroll
                    for (int j = 0; j < HB; ++j) {
                        const float xv = (j < 4) ? xs0[j & 3] : xs1[j & 3];
                        // x-FMA folded into acc init (off the post-dot tail)
                        float a0 = fmaf(wx4[0], xv, b1v[0]);
                        float a1 = fmaf(wx4[1], xv, b1v[1]);
                        float a2 = fmaf(wx4[2], xv, b1v[2]);
                        float a3 = fmaf(wx4[3], xv, b1v[3]);
                        float b0 = 0.0f, b1 = 0.0f, b2 = 0.0f, b3 = 0.0f;
                        const int _hs = hpk1reg;
                        DOT26
                        const float ig = sigmoidf_fast(a0 + b0), fg = sigmoidf_fast(a1 + b1);
                        const float gg = tanhf_fast(a2 + b2),    og = sigmoidf_fast(a3 + b3);
                        c1 = fmaf(fg, c1, ig * gg);
                        const float h1n = (lane < H) ? og * tanhf_fast(c1) : 0.0f;
                        hpk1reg = packpairs_dpp(h1n);
                        sh_hpk1[e & 1][hb * HB + j][lane] = hpk1reg;
                    }
                }
            }
        } else if (wave == 2) {
            // ---- steps 32(e-1)+j: z2a = Wih2.h1 (32 indep dots, 4 blocks) ----
            if (e >= 1 && e <= TSTEPS / SE) {
                const int rb = (e - 1) & 1;
#pragma unroll 1
                for (int hb = 0; hb < NB; ++hb) {
                    int hp[HB];
#pragma unroll
                    for (int jj = 0; jj < HB; ++jj)
                        hp[jj] = sh_hpk1[rb][hb * HB + jj][lane];
#pragma unroll
                    for (int jj = 0; jj < HB; ++jj) {
                        const int _hs = hp[jj];
                        float a0 = 0.0f, a1 = 0.0f, a2 = 0.0f, a3 = 0.0f;
                        float b0 = 0.0f, b1 = 0.0f, b2 = 0.0f, b3 = 0.0f;
                        DOT26
                        f4 z; z[0] = a0 + b0; z[1] = a1 + b1; z[2] = a2 + b2; z[3] = a3 + b3;
                        sh_z2a[e & 1][hb * HB + jj][lane] = z;
                    }
                }
            }
        } else if (wave == 1) {
            // ---- steps 32(e-2)+j: u2 dot (in-wave h2 self-loop) + cell2 ----
            if (e >= 2 && e <= TSTEPS / SE + 1) {
                const int rb = (e - 1) & 1;
#pragma unroll 1
                for (int hb = 0; hb < NB; ++hb) {
                    f4 za[HB];
#pragma unroll
                    for (int jj = 0; jj < HB; ++jj)
                        za[jj] = sh_z2a[rb][hb * HB + jj][lane];
#pragma unroll
                    for (int jj = 0; jj < HB; ++jj) {
                        float a0 = b2v[0], a1 = b2v[1], a2 = b2v[2], a3 = b2v[3];
                        float b0 = 0.0f, b1 = 0.0f, b2 = 0.0f, b3 = 0.0f;
                        const int _hs = hpk2reg;
                        DOT26
                        const float ig = sigmoidf_fast(za[jj][0] + a0 + b0);
                        const float fg = sigmoidf_fast(za[jj][1] + a1 + b1);
                        const float gg = tanhf_fast   (za[jj][2] + a2 + b2);
                        const float og = sigmoidf_fast(za[jj][3] + a3 + b3);
                        c2 = fmaf(fg, c2, ig * gg);
                        const float h2n = (lane < H) ? og * tanhf_fast(c2) : 0.0f;
                        sh_h2f[e & 1][hb * HB + jj][lane] = h2n;
                        hpk2reg = packpairs_dpp(h2n);
                    }
                }
            }
        } else {
            // ---- steps 32(e-3)+j: out = Wlin.h2 + blin (off-path, direct
            // global store) ----
            if (e >= 3) {
                const int base = (e - 3) * SE;
                const int rb = (e - 1) & 1;
#pragma unroll 1
                for (int hb = 0; hb < NB; ++hb) {
                    float p[HB];
#pragma unroll
                    for (int jj = 0; jj < HB; ++jj)
                        p[jj] = sh_h2f[rb][hb * HB + jj][lane] * wlin;
#pragma unroll
                    for (int off = 32; off >= 1; off >>= 1) {
#pragma unroll
                        for (int jj = 0; jj < HB; ++jj) p[jj] += __shfl_down(p[jj], off);
                    }
                    if (lane == 0) {
#pragma unroll
                        for (int jj = 0; jj < HB; ++jj) out[base + hb * HB + jj] = p[jj] + bl;
                    }
                }
            }
        }
        __syncthreads();
    }
}

extern "C" void kernel_launch(void* const* d_in, const int* in_sizes, int n_in,
                              void* d_out, int out_size, void* d_ws, size_t ws_size,
                              hipStream_t stream) {
    const float* x    = (const float*)d_in[0];
    const float* Wih1 = (const float*)d_in[1];
    const float* Whh1 = (const float*)d_in[2];
    const float* bih1 = (const float*)d_in[3];
    const float* bhh1 = (const float*)d_in[4];
    const float* Wih2 = (const float*)d_in[5];
    const float* Whh2 = (const float*)d_in[6];
    const float* bih2 = (const float*)d_in[7];
    const float* bhh2 = (const float*)d_in[8];
    const float* Wlin = (const float*)d_in[9];
    const float* blin = (const float*)d_in[10];
    float* out = (float*)d_out;

    lstm2_r25_kernel<<<1, 256, 0, stream>>>(
        x, Wih1, Whh1, bih1, bhh1, Wih2, Whh2, bih2, bhh2, Wlin, blin, out);
}

// Round 8
// 2999.444 us; speedup vs baseline: 1.8880x; 1.0103x over previous
//
#include <hip/hip_runtime.h>

#define TSTEPS 8192
#define H 51
#define SE 16                    // timesteps per barrier epoch (R21 config)
#define NEPOCH (TSTEPS / SE + 3) // 4 pipeline stages -> +3 epochs

typedef float  f2 __attribute__((ext_vector_type(2)));
typedef float  f4 __attribute__((ext_vector_type(4)));
typedef int    i4 __attribute__((ext_vector_type(4)));
typedef int    i2 __attribute__((ext_vector_type(2)));
typedef _Float16 h2 __attribute__((ext_vector_type(2)));

__device__ __forceinline__ int rl_i(int v, int k) { return __builtin_amdgcn_readlane(v, k); }
__device__ __forceinline__ h2 asp(int v) { union { int i; h2 h; } u; u.i = v; return u.h; }
__device__ __forceinline__ int ash(h2 v) { union { int i; h2 h; } u; u.h = v; return u.i; }

__device__ __forceinline__ float fdot2(h2 a, h2 b, float c) {
#if __has_builtin(__builtin_amdgcn_fdot2)
    return __builtin_amdgcn_fdot2(a, b, c, false);
#else
    return fmaf((float)a[0], (float)b[0], fmaf((float)a[1], (float)b[1], c));
#endif
}
__device__ __forceinline__ float sigmoidf_fast(float x) {
    return __builtin_amdgcn_rcpf(1.0f + __expf(-x));
}
__device__ __forceinline__ float tanhf_fast(float x) {
    x = fminf(fmaxf(x, -15.0f), 15.0f);
    float t = __expf(-2.0f * x);
    return (1.0f - t) * __builtin_amdgcn_rcpf(1.0f + t);
}
__device__ __forceinline__ int packpair(const float* Wrow, int j) {
    const float w0 = (2 * j < H) ? Wrow[2 * j] : 0.0f;
    const float w1 = (2 * j + 1 < H) ? Wrow[2 * j + 1] : 0.0f;
    h2 p; p[0] = (_Float16)w0; p[1] = (_Float16)w1; return ash(p);
}
// R21: pure-VALU pack (DPP quad_perm neighbor + RNE f16 pair), no DS pipe.
// Measured: bank-conflict 65536 -> 0, -232 us. Even lane 2j holds
// {h[2j], h[2j+1]}; DOT26 broadcasts from lane 2j.
__device__ __forceinline__ int packpairs_dpp(float hval) {
    const int nbi = __builtin_amdgcn_mov_dpp(__float_as_int(hval), 0xB1, 0xF, 0xF, true);
    h2 pk; pk[0] = (_Float16)hval; pk[1] = (_Float16)__int_as_float(nbi);
    return ash(pk);
}

// R26 = R21 (best measured, 2940 us rocprof) with ONE isolated change:
// DOT26's readlane is software-pipelined one group ahead. Theory: each
// group's dots consume the SGPR written by the readlane issued 0 instrs
// earlier -> ~4-5 wait states x 26 groups ~ 100 cyc/step hazard stall on
// all 3 DOT26 waves. R16 bundled this hoist with the log2e fold; R17
// proved the fold ALONE regresses -> the hoist is untested in isolation.
// Dot order, acc interleave, tail: byte-identical to R21.
// Ledger (rocprof): R19 SE8 3168 | R20 SE16 3172 | R21 +DPP 2940 best |
// R22 body-edits 3372 | R23 SE32-unroll 5830 (I$) | R24 SE32-roll 3273 |
// R25 SE32-blk8 2964. Barrier amort ~0; I$ binds >60KB; blk overhead 24us.
// Fallback (pre-committed): if this regresses, resubmit R21 verbatim.
// Pipeline (R13 lineage):
//   wave0 @e: steps 16e..16e+15 : h1 = cell1(Whh1.h1 + x)  [in-wave serial]
//   wave2 @e: steps 16(e-1)+j   : z2a = Wih2.h1            [16 indep dots]
//   wave1 @e: steps 16(e-2)+j   : u2 dot (in-wave) + cell2 [in-wave serial]
//   wave3 @e: steps 16(e-3)+j   : out = Wlin.h2 + blin     [off-path]
// Invariants: (1) no DS ops on the serial chain (R21). (2) asm "+v" PIN
// once (R7). (3) tail/math sacred (R14-R17, R22). (4) hot code <= ~60KB
// (R23/R24).
#define DECLG(g) i4 wq##g##_0, wq##g##_1, wq##g##_2, wq##g##_3, wq##g##_4, wq##g##_5; i2 wq##g##_6;
#define LOADG(g, RP) { const float* _r = (RP); \
    i4 t0 = {packpair(_r,0),  packpair(_r,1),  packpair(_r,2),  packpair(_r,3)};  wq##g##_0 = t0; \
    i4 t1 = {packpair(_r,4),  packpair(_r,5),  packpair(_r,6),  packpair(_r,7)};  wq##g##_1 = t1; \
    i4 t2 = {packpair(_r,8),  packpair(_r,9),  packpair(_r,10), packpair(_r,11)}; wq##g##_2 = t2; \
    i4 t3 = {packpair(_r,12), packpair(_r,13), packpair(_r,14), packpair(_r,15)}; wq##g##_3 = t3; \
    i4 t4 = {packpair(_r,16), packpair(_r,17), packpair(_r,18), packpair(_r,19)}; wq##g##_4 = t4; \
    i4 t5 = {packpair(_r,20), packpair(_r,21), packpair(_r,22), packpair(_r,23)}; wq##g##_5 = t5; \
    i2 t6 = {packpair(_r,24), packpair(_r,25)};                                   wq##g##_6 = t6; }
#define PING(g) asm("" : "+v"(wq##g##_0), "+v"(wq##g##_1), "+v"(wq##g##_2), \
                        "+v"(wq##g##_3), "+v"(wq##g##_4), "+v"(wq##g##_5), "+v"(wq##g##_6));
// two interleaved accumulator sets: a* (even j) and b* (odd j) -> depth 13.
// R26: readlane for group j+1 issued BEFORE group j's dots consume _sc ->
// ~10 covering cycles between SGPR write and first use.
#define DJAP(j,q,e) { const int _sn = rl_i(_hs, 2*((j)+1)); \
    const h2 _hb = asp(_sc); \
    a0 = fdot2(asp(wq0_##q[e]), _hb, a0); \
    a1 = fdot2(asp(wq1_##q[e]), _hb, a1); \
    a2 = fdot2(asp(wq2_##q[e]), _hb, a2); \
    a3 = fdot2(asp(wq3_##q[e]), _hb, a3); \
    _sc = _sn; }
#define DJBP(j,q,e) { const int _sn = rl_i(_hs, 2*((j)+1)); \
    const h2 _hb = asp(_sc); \
    b0 = fdot2(asp(wq0_##q[e]), _hb, b0); \
    b1 = fdot2(asp(wq1_##q[e]), _hb, b1); \
    b2 = fdot2(asp(wq2_##q[e]), _hb, b2); \
    b3 = fdot2(asp(wq3_##q[e]), _hb, b3); \
    _sc = _sn; }
#define DJBL(j,q,e) { const h2 _hb = asp(_sc); \
    b0 = fdot2(asp(wq0_##q[e]), _hb, b0); \
    b1 = fdot2(asp(wq1_##q[e]), _hb, b1); \
    b2 = fdot2(asp(wq2_##q[e]), _hb, b2); \
    b3 = fdot2(asp(wq3_##q[e]), _hb, b3); }
#define DOT26 { int _sc = rl_i(_hs, 0); \
    DJAP(0,0,0) DJBP(1,0,1) DJAP(2,0,2) DJBP(3,0,3) DJAP(4,1,0) DJBP(5,1,1) DJAP(6,1,2) DJBP(7,1,3) \
    DJAP(8,2,0) DJBP(9,2,1) DJAP(10,2,2) DJBP(11,2,3) DJAP(12,3,0) DJBP(13,3,1) DJAP(14,3,2) DJBP(15,3,3) \
    DJAP(16,4,0) DJBP(17,4,1) DJAP(18,4,2) DJBP(19,4,3) DJAP(20,5,0) DJBP(21,5,1) DJAP(22,5,2) DJBP(23,5,3) \
    DJAP(24,6,0) DJBL(25,6,1) }

__global__ __launch_bounds__(256) __attribute__((amdgpu_waves_per_eu(1, 1)))
void lstm2_r26_kernel(const float* __restrict__ x,
                      const float* __restrict__ Wih1,
                      const float* __restrict__ Whh1,
                      const float* __restrict__ bih1,
                      const float* __restrict__ bhh1,
                      const float* __restrict__ Wih2,
                      const float* __restrict__ Whh2,
                      const float* __restrict__ bih2,
                      const float* __restrict__ bhh2,
                      const float* __restrict__ Wlin,
                      const float* __restrict__ blin,
                      float* __restrict__ out)
{
    __shared__ __align__(16) float sh_x[TSTEPS];
    __shared__ __align__(16) float sh_out[TSTEPS];
    __shared__ __align__(16) int   sh_hpk1[2][SE][64];  // packed h1 (wave0 -> wave2)
    __shared__ __align__(16) f4    sh_z2a[2][SE][64];   // raw Wih2.h1 (wave2 -> wave1)
    __shared__ __align__(16) float sh_h2f[2][SE][64];   // f32 h2 (wave1 -> wave3)

    const int tid  = threadIdx.x;
    const int wave = tid >> 6;
    const int lane = tid & 63;
    const int row  = (lane < H) ? lane : (H - 1);

    for (int i = tid; i < TSTEPS / 4; i += 256)
        ((f4*)sh_x)[i] = ((const f4*)x)[i];

    // ---- per-wave matrix as 104 packed f16-pair registers, pinned once ----
    const float* Mp = (wave == 0) ? Whh1 : (wave == 1) ? Whh2 : Wih2;
    DECLG(0) DECLG(1) DECLG(2) DECLG(3)
    LOADG(0, Mp + (0 * H + row) * H)
    LOADG(1, Mp + (1 * H + row) * H)
    LOADG(2, Mp + (2 * H + row) * H)
    LOADG(3, Mp + (3 * H + row) * H)
    PING(0) PING(1) PING(2) PING(3)

    f4 b1v, wx4, b2v;
#pragma unroll
    for (int g = 0; g < 4; ++g) {
        b1v[g] = bih1[g * H + row] + bhh1[g * H + row];
        wx4[g] = Wih1[g * H + row];
        b2v[g] = bih2[g * H + row] + bhh2[g * H + row];
    }
    const float wlin = (lane < H) ? Wlin[lane] : 0.0f;
    const float bl   = blin[0];

    if (tid < 64) {
#pragma unroll
        for (int b = 0; b < 2; ++b)
#pragma unroll
            for (int j = 0; j < SE; ++j) {
                sh_hpk1[b][j][tid] = 0;
                sh_z2a[b][j][tid] = (f4)0.0f;
                sh_h2f[b][j][tid] = 0.0f;
            }
    }
    float c1 = 0.0f, c2 = 0.0f;
    int hpk1reg = 0, hpk2reg = 0;
    __syncthreads();

#pragma unroll 1
    for (int e = 0; e < NEPOCH; ++e) {
        if (wave == 0) {
            // ---- steps 16e..16e+15: layer-1 self-loop, fully in-wave ----
            if (e < TSTEPS / SE) {
                f4 xs[4];
#pragma unroll
                for (int q = 0; q < 4; ++q) xs[q] = ((const f4*)sh_x)[4 * e + q];
#pragma unroll
                for (int j = 0; j < SE; ++j) {
                    const float xv = xs[j >> 2][j & 3];
                    // x-FMA folded into acc init (off the post-dot tail)
                    float a0 = fmaf(wx4[0], xv, b1v[0]);
                    float a1 = fmaf(wx4[1], xv, b1v[1]);
                    float a2 = fmaf(wx4[2], xv, b1v[2]);
                    float a3 = fmaf(wx4[3], xv, b1v[3]);
                    float b0 = 0.0f, b1 = 0.0f, b2 = 0.0f, b3 = 0.0f;
                    const int _hs = hpk1reg;
                    DOT26
                    const float ig = sigmoidf_fast(a0 + b0), fg = sigmoidf_fast(a1 + b1);
                    const float gg = tanhf_fast(a2 + b2),    og = sigmoidf_fast(a3 + b3);
                    c1 = fmaf(fg, c1, ig * gg);
                    const float h1n = (lane < H) ? og * tanhf_fast(c1) : 0.0f;
                    hpk1reg = packpairs_dpp(h1n);
                    sh_hpk1[e & 1][j][lane] = hpk1reg;
                }
            }
        } else if (wave == 2) {
            // ---- steps 16(e-1)+j: z2a = Wih2.h1 (16 indep dots, 2 halves) ----
            if (e >= 1 && e <= TSTEPS / SE) {
#pragma unroll
                for (int hb = 0; hb < 2; ++hb) {
                    int hp[SE / 2];
#pragma unroll
                    for (int jj = 0; jj < SE / 2; ++jj)
                        hp[jj] = sh_hpk1[(e - 1) & 1][hb * (SE / 2) + jj][lane];
#pragma unroll
                    for (int jj = 0; jj < SE / 2; ++jj) {
                        const int _hs = hp[jj];
                        float a0 = 0.0f, a1 = 0.0f, a2 = 0.0f, a3 = 0.0f;
                        float b0 = 0.0f, b1 = 0.0f, b2 = 0.0f, b3 = 0.0f;
                        DOT26
                        f4 z; z[0] = a0 + b0; z[1] = a1 + b1; z[2] = a2 + b2; z[3] = a3 + b3;
                        sh_z2a[e & 1][hb * (SE / 2) + jj][lane] = z;
                    }
                }
            }
        } else if (wave == 1) {
            // ---- steps 16(e-2)+j: u2 dot (in-wave h2 self-loop) + cell2 ----
            // two half-blocks of 8: za prefetch stays at 32 VGPR (spill cliff)
            if (e >= 2 && e <= TSTEPS / SE + 1) {
#pragma unroll
                for (int hb = 0; hb < 2; ++hb) {
                    f4 za[SE / 2];
#pragma unroll
                    for (int jj = 0; jj < SE / 2; ++jj)
                        za[jj] = sh_z2a[(e - 1) & 1][hb * (SE / 2) + jj][lane];
#pragma unroll
                    for (int jj = 0; jj < SE / 2; ++jj) {
                        float a0 = b2v[0], a1 = b2v[1], a2 = b2v[2], a3 = b2v[3];
                        float b0 = 0.0f, b1 = 0.0f, b2 = 0.0f, b3 = 0.0f;
                        const int _hs = hpk2reg;
                        DOT26
                        const float ig = sigmoidf_fast(za[jj][0] + a0 + b0);
                        const float fg = sigmoidf_fast(za[jj][1] + a1 + b1);
                        const float gg = tanhf_fast   (za[jj][2] + a2 + b2);
                        const float og = sigmoidf_fast(za[jj][3] + a3 + b3);
                        c2 = fmaf(fg, c2, ig * gg);
                        const float h2n = (lane < H) ? og * tanhf_fast(c2) : 0.0f;
                        sh_h2f[e & 1][hb * (SE / 2) + jj][lane] = h2n;
                        hpk2reg = packpairs_dpp(h2n);
                    }
                }
            }
        } else {
            // ---- steps 16(e-3)+j: out = Wlin.h2 + blin (off critical path) ----
            if (e >= 3) {
                const int base = (e - 3) * SE;
                float p[SE];
#pragma unroll
                for (int j = 0; j < SE; ++j)
                    p[j] = sh_h2f[(e - 1) & 1][j][lane] * wlin;
#pragma unroll
                for (int off = 32; off >= 1; off >>= 1) {
#pragma unroll
                    for (int j = 0; j < SE; ++j) p[j] += __shfl_down(p[j], off);
                }
                if (lane == 0) {
#pragma unroll
                    for (int j = 0; j < SE; ++j) sh_out[base + j] = p[j] + bl;
                }
            }
        }
        __syncthreads();
    }

    for (int i = tid; i < TSTEPS / 4; i += 256)
        ((f4*)out)[i] = ((const f4*)sh_out)[i];
}

extern "C" void kernel_launch(void* const* d_in, const int* in_sizes, int n_in,
                              void* d_out, int out_size, void* d_ws, size_t ws_size,
                              hipStream_t stream) {
    const float* x    = (const float*)d_in[0];
    const float* Wih1 = (const float*)d_in[1];
    const float* Whh1 = (const float*)d_in[2];
    const float* bih1 = (const float*)d_in[3];
    const float* bhh1 = (const float*)d_in[4];
    const float* Wih2 = (const float*)d_in[5];
    const float* Whh2 = (const float*)d_in[6];
    const float* bih2 = (const float*)d_in[7];
    const float* bhh2 = (const float*)d_in[8];
    const float* Wlin = (const float*)d_in[9];
    const float* blin = (const float*)d_in[10];
    float* out = (float*)d_out;

    lstm2_r26_kernel<<<1, 256, 0, stream>>>(
        x, Wih1, Whh1, bih1, bhh1, Wih2, Whh2, bih2, bhh2, Wlin, blin, out);
}